// Round 6
// baseline (208.032 us; speedup 1.0000x reference)
//
#include <hip/hip_runtime.h>

// Problem constants (from reference: M, B, D = 32, 64, 8192)
#define Mh 32
#define Bh 64
#define Dh 8192
#define KCH 256           // K-range per workgroup in gram kernel
#define NCH (Dh / KCH)    // 32 k-chunks -> 2048 blocks
#define CCH 8             // d-chunks for combine

// Workspace layout (float offsets). Base ~545 KB + 16.5 MB slab.
#define OFF_WSY 0                       // [64][32][32]  (atomic-fallback only)
#define OFF_WYY (64 * 1024)             // [64][32][32]  (atomic-fallback only)
#define OFF_VS  (2 * 64 * 1024)         // [64][32]      (atomic-fallback only)
#define OFF_VY  (OFF_VS + 64 * 32)      // [64][32]      (atomic-fallback only)
#define OFF_CY  (OFF_VY + 64 * 32)      // [64][32]      g * a_i
#define OFF_CS  (OFF_CY + 64 * 32)      // [64][32]      b_i - a_i
#define OFF_G   (OFF_CS + 64 * 32)      // [64]          g per batch
#define WS_ZERO_FLOATS OFF_CY           // atomic-path zero region
// Gram partial slabs (slab path): PSY[ch][b][1024], PYY[ch][b][1024]
#define OFF_PART (OFF_G + 64)
#define PART_FLOATS (NCH * 64 * 1024)   // per matrix: 8 MB
// vs/vy partial slabs: PVS[ch][b][32], PVY[ch][b][32]
#define OFF_VPS (OFF_PART + 2 * PART_FLOATS)
#define OFF_VPY (OFF_VPS + NCH * 64 * 32)
#define WS_END  (OFF_VPY + NCH * 64 * 32)

typedef __attribute__((ext_vector_type(8)))  __bf16 bf16x8;
typedef __attribute__((ext_vector_type(16))) float  f32x16;

__device__ __forceinline__ float dot4(const float4 a, const float4 b)
{ return a.x * b.x + a.y * b.y + a.z * b.z + a.w * b.w; }

// fp32x8 -> bf16 hi/lo split: x ~= hi + lo with |err| ~ 2^-18 |x|
__device__ __forceinline__ void split8(const float4 a, const float4 b,
                                       bf16x8& h, bf16x8& lo)
{
    const float x[8] = {a.x, a.y, a.z, a.w, b.x, b.y, b.z, b.w};
    #pragma unroll
    for (int e = 0; e < 8; ++e) {
        h[e]  = (__bf16)x[e];
        lo[e] = (__bf16)(x[e] - (float)h[e]);
    }
}

// ---------------------------------------------------------------------------
// Kernel A: batched Gram matrices via bf16-split MFMA, ZERO-LDS main loop.
// grid = 64 b x 32 k-chunks, 256 threads (4 waves), wave w owns 64 k.
// Rounds 3-5 evidence: staged-atomic, staged-slab and burst-global_load_lds
// all land at 46-51 us with every pipe idle -> latency-bound at <=2
// blocks/CU (64 KB LDS cap). Key fact: the 32x32x16 A-frag and B-frag have
// the SAME lane->(row,k) map (lane l = row l&31, 8 consecutive k at
// 8*(l>>5)), harness-verified in r3-r5 via aYH feeding both operands. So
// each lane loads its fragments DIRECTLY from global (2 float4/tensor/step,
// offset-immediate folded); LDS staging deleted. Main loop: no barriers, no
// LDS ops; LDS (33 KB, epilogue reduce only) -> 4 blocks/CU; free-running
// waves with ~12 outstanding VMEM each = max MLP. Lanes l and l+32 consume
// the two halves of each 64-B line -> full line utilization.
// frc-dots ride the same fragment regs in exact fp32. vs/vy -> slab
// partials (no atomics => launcher needs NO memset on the slab path).
// NO min-waves launch_bounds clamp (round-1: clamp -> spill -> 987 us).
// ---------------------------------------------------------------------------
template <int SLAB>
__global__ __launch_bounds__(256) void gram_kernel(
    const float* __restrict__ s, const float* __restrict__ y,
    const float* __restrict__ frc, float* __restrict__ ws)
{
    __shared__ float RS[4][1024];      // per-wave Wsy partials (16 KB)
    __shared__ float RY[4][1024];      // per-wave Wyy partials (16 KB)
    __shared__ float fVS[4][32], fVY[4][32];

    const int b  = blockIdx.x & 63;
    const int ch = blockIdx.x >> 6;
    const int t  = threadIdx.x;
    const int w  = t >> 6;        // wave 0..3 -> k-window [64w, 64w+64)
    const int l  = t & 63;
    const int r  = l & 31;        // fragment row (= col for B use)
    const int h  = l >> 5;        // k-half within each 16-k step

    const size_t kb = (size_t)ch * KCH + (w << 6) + (h << 3);
    const float* sp = s + ((size_t)r * Bh + b) * Dh + kb;
    const float* yp = y + ((size_t)r * Bh + b) * Dh + kb;
    const float* fp = frc + (size_t)b * Dh + kb;

    f32x16 accSY = {};
    f32x16 accYY = {};
    float avs = 0.f, avy = 0.f;

    // 1-step software pipeline over the 4 16-k steps of this wave's window
    float4 sa[2], sb[2], ya[2], yb[2], fa[2], fb[2];
    sa[0] = *(const float4*)(sp);     sb[0] = *(const float4*)(sp + 4);
    ya[0] = *(const float4*)(yp);     yb[0] = *(const float4*)(yp + 4);
    fa[0] = *(const float4*)(fp);     fb[0] = *(const float4*)(fp + 4);
    #pragma unroll
    for (int j = 0; j < 4; ++j) {
        const int c = j & 1, n = c ^ 1;
        if (j < 3) {
            const int o = (j + 1) << 4;
            sa[n] = *(const float4*)(sp + o);  sb[n] = *(const float4*)(sp + o + 4);
            ya[n] = *(const float4*)(yp + o);  yb[n] = *(const float4*)(yp + o + 4);
            fa[n] = *(const float4*)(fp + o);  fb[n] = *(const float4*)(fp + o + 4);
        }
        // exact-fp32 frc dot partials (lane covers row r, its 8-k slice)
        avs += dot4(sa[c], fa[c]) + dot4(sb[c], fb[c]);
        avy += dot4(ya[c], fa[c]) + dot4(yb[c], fb[c]);

        bf16x8 aSH, aSL, aYH, aYL;
        split8(sa[c], sb[c], aSH, aSL);
        split8(ya[c], yb[c], aYH, aYL);
        accSY = __builtin_amdgcn_mfma_f32_32x32x16_bf16(aSH, aYH, accSY, 0, 0, 0);
        accYY = __builtin_amdgcn_mfma_f32_32x32x16_bf16(aYH, aYH, accYY, 0, 0, 0);
        accSY = __builtin_amdgcn_mfma_f32_32x32x16_bf16(aSH, aYL, accSY, 0, 0, 0);
        accYY = __builtin_amdgcn_mfma_f32_32x32x16_bf16(aYH, aYL, accYY, 0, 0, 0);
        accSY = __builtin_amdgcn_mfma_f32_32x32x16_bf16(aSL, aYH, accSY, 0, 0, 0);
        accYY = __builtin_amdgcn_mfma_f32_32x32x16_bf16(aYL, aYH, accYY, 0, 0, 0);
    }

    // vs/vy: lanes l and l+32 hold the two k-halves of row r
    avs += __shfl_xor(avs, 32);
    avy += __shfl_xor(avy, 32);
    if (h == 0) { fVS[w][r] = avs; fVY[w][r] = avy; }

    // per-wave 32x32 partials to LDS; C/D map: col=l&31,
    // row = (rr&3) + 8*(rr>>2) + 4*(l>>5)   [r3-r5 harness-verified]
    #pragma unroll
    for (int rr = 0; rr < 16; ++rr) {
        const int i = (rr & 3) + ((rr >> 2) << 3) + (h << 2);
        RS[w][i * 32 + r] = accSY[rr];
        RY[w][i * 32 + r] = accYY[rr];
    }
    __syncthreads();

    if (SLAB) {
        float* PS = ws + OFF_PART + ((size_t)(ch * 64 + b)) * 1024;
        float* PY = ws + OFF_PART + PART_FLOATS + ((size_t)(ch * 64 + b)) * 1024;
        const int e4 = t << 2;
        float4 o0, o1;
        const float4 a0 = *(const float4*)&RS[0][e4];
        const float4 a1 = *(const float4*)&RS[1][e4];
        const float4 a2 = *(const float4*)&RS[2][e4];
        const float4 a3 = *(const float4*)&RS[3][e4];
        o0.x = a0.x + a1.x + a2.x + a3.x;  o0.y = a0.y + a1.y + a2.y + a3.y;
        o0.z = a0.z + a1.z + a2.z + a3.z;  o0.w = a0.w + a1.w + a2.w + a3.w;
        *(float4*)&PS[e4] = o0;
        const float4 c0 = *(const float4*)&RY[0][e4];
        const float4 c1 = *(const float4*)&RY[1][e4];
        const float4 c2 = *(const float4*)&RY[2][e4];
        const float4 c3 = *(const float4*)&RY[3][e4];
        o1.x = c0.x + c1.x + c2.x + c3.x;  o1.y = c0.y + c1.y + c2.y + c3.y;
        o1.z = c0.z + c1.z + c2.z + c3.z;  o1.w = c0.w + c1.w + c2.w + c3.w;
        *(float4*)&PY[e4] = o1;
        if (t < 32) {
            ws[OFF_VPS + ((size_t)(ch * 64 + b)) * 32 + t] =
                fVS[0][t] + fVS[1][t] + fVS[2][t] + fVS[3][t];
        } else if (t < 64) {
            const int i = t - 32;
            ws[OFF_VPY + ((size_t)(ch * 64 + b)) * 32 + i] =
                fVY[0][i] + fVY[1][i] + fVY[2][i] + fVY[3][i];
        }
    } else {
        float* WSY = ws + OFF_WSY + b * 1024;
        float* WYY = ws + OFF_WYY + b * 1024;
        for (int e = t; e < 1024; e += 256) {
            unsafeAtomicAdd(&WSY[e], RS[0][e] + RS[1][e] + RS[2][e] + RS[3][e]);
            unsafeAtomicAdd(&WYY[e], RY[0][e] + RY[1][e] + RY[2][e] + RY[3][e]);
        }
        if (t < 32) {
            unsafeAtomicAdd(&ws[OFF_VS + b * 32 + t],
                            fVS[0][t] + fVS[1][t] + fVS[2][t] + fVS[3][t]);
        } else if (t < 64) {
            const int i = t - 32;
            unsafeAtomicAdd(&ws[OFF_VY + b * 32 + i],
                            fVY[0][i] + fVY[1][i] + fVY[2][i] + fVY[3][i]);
        }
    }
}

// ---------------------------------------------------------------------------
// Kernel B (fused): slab-reduce the Gram + vs/vy partials into LDS, then
// run the per-b M=32 f64 recursion from LDS. grid = 64 blocks x 256 thr.
// ---------------------------------------------------------------------------
template <int SLAB>
__global__ __launch_bounds__(256) void recur_kernel(float* __restrict__ ws)
{
    __shared__ float WSY_l[1024], WYY_l[1024];
    __shared__ float vsL[32], vyL[32];
    const int b = blockIdx.x;
    const int t = threadIdx.x;

    if (SLAB) {
        const int e4 = t << 2;
        const float* PS = ws + OFF_PART;
        const float* PY = ws + OFF_PART + PART_FLOATS;
        float4 a = make_float4(0.f, 0.f, 0.f, 0.f);
        float4 c = make_float4(0.f, 0.f, 0.f, 0.f);
        #pragma unroll
        for (int ch = 0; ch < NCH; ++ch) {
            const size_t o = ((size_t)(ch * 64 + b)) * 1024 + e4;
            const float4 v = *(const float4*)&PS[o];
            const float4 u = *(const float4*)&PY[o];
            a.x += v.x; a.y += v.y; a.z += v.z; a.w += v.w;
            c.x += u.x; c.y += u.y; c.z += u.z; c.w += u.w;
        }
        *(float4*)&WSY_l[e4] = a;
        *(float4*)&WYY_l[e4] = c;
        if (t < 64) {
            const int i = t & 31;
            const float* PV = ws + (t < 32 ? OFF_VPS : OFF_VPY);
            float acc = 0.f;
            #pragma unroll
            for (int ch = 0; ch < NCH; ++ch)
                acc += PV[((size_t)(ch * 64 + b)) * 32 + i];
            (t < 32 ? vsL : vyL)[i] = acc;
        }
    } else {
        for (int e = t; e < 1024; e += 256) {
            WSY_l[e] = ws[OFF_WSY + b * 1024 + e];
            WYY_l[e] = ws[OFF_WYY + b * 1024 + e];
        }
        if (t < 32)       vsL[t] = ws[OFF_VS + b * 32 + t];
        else if (t < 64)  vyL[t - 32] = ws[OFF_VY + b * 32 + (t - 32)];
    }
    __syncthreads();

    if (t < 64) {
        const int lane = t;
        const int i = lane & 31;   // lanes 32..63 mirror 0..31 (writes guarded)

        float row_sy[32], col_sy[32], row_yy[32];
        #pragma unroll
        for (int j = 0; j < 32; ++j) {
            row_sy[j] = WSY_l[i * 32 + j];   // s_i . y_j
            col_sy[j] = WSY_l[j * 32 + i];   // s_j . y_i
            row_yy[j] = WYY_l[i * 32 + j];   // y_i . y_j
        }

        const double r = 1.0 / (double)row_sy[i];          // 1/(s_i.y_i)
        double acc = -(double)vsL[i];                      // s_i.q0 running
        double a_val = 0.0;
        #pragma unroll
        for (int j = 31; j >= 0; --j) {                    // backward scan
            const double aj = __shfl(r, j) * __shfl(acc, j);
            if (i == j) a_val = aj;
            if (i < j)  acc -= aj * (double)row_sy[j];
        }

        const double g = (double)WSY_l[31 * 32 + 31] / (double)WYY_l[31 * 32 + 31];

        double u = -(double)vyL[i];                        // y_i.q_f0 / g
        #pragma unroll
        for (int j = 0; j < 32; ++j)
            u -= __shfl(a_val, j) * (double)row_yy[j];
        u *= g;

        double tt = u;
        double b_val = 0.0;
        #pragma unroll
        for (int j = 0; j < 32; ++j) {                     // forward scan
            const double bj = __shfl(r, j) * __shfl(tt, j);
            if (i == j) b_val = bj;
            const double dj = __shfl(a_val, j) - bj;
            if (i > j) tt += dj * (double)col_sy[j];
        }

        if (lane < 32) {
            ws[OFF_CY + b * 32 + i] = (float)(g * a_val);
            ws[OFF_CS + b * 32 + i] = (float)(b_val - a_val);
        }
        if (lane == 0) ws[OFF_G + b] = (float)g;
    }
}

// ---------------------------------------------------------------------------
// Kernel C: out[b,d] = g*frc[b,d] + sum_i cy[i]*y[i,b,d] + cs[i]*s[i,b,d]
// grid = 64 b x 8 d-chunks, 1024 threads (16 waves). i-sum split 4-way
// across thread quarters, LDS tree reduce at end. (unchanged)
// ---------------------------------------------------------------------------
__global__ __launch_bounds__(1024) void combine_kernel(
    const float* __restrict__ s, const float* __restrict__ y,
    const float* __restrict__ frc, const float* __restrict__ ws,
    float* __restrict__ out)
{
    __shared__ float cy[32], cs[32];
    __shared__ float4 red[3][256];
    const int b  = blockIdx.x & 63;
    const int ch = blockIdx.x >> 6;
    const int t  = threadIdx.x;
    const int q  = t >> 8;          // quarter 0..3: i in [8q, 8q+8)
    const int tt = t & 255;
    if (t < 32) { cy[t] = ws[OFF_CY + b * 32 + t]; cs[t] = ws[OFF_CS + b * 32 + t]; }
    __syncthreads();

    const int d = ch * 1024 + (tt << 2);
    float4 acc = make_float4(0.f, 0.f, 0.f, 0.f);
    if (q == 0) {
        const float g = ws[OFF_G + b];
        const float4 fv = *(const float4*)(frc + (size_t)b * Dh + d);
        acc.x = g * fv.x; acc.y = g * fv.y; acc.z = g * fv.z; acc.w = g * fv.w;
    }
    const int ib = q << 3;
    #pragma unroll
    for (int i2 = 0; i2 < 8; ++i2) {
        const int i = ib + i2;
        const float4 yv = *(const float4*)(y + ((size_t)i * Bh + b) * Dh + d);
        const float4 sv = *(const float4*)(s + ((size_t)i * Bh + b) * Dh + d);
        const float a1 = cy[i], a2 = cs[i];
        acc.x += a1 * yv.x + a2 * sv.x;
        acc.y += a1 * yv.y + a2 * sv.y;
        acc.z += a1 * yv.z + a2 * sv.z;
        acc.w += a1 * yv.w + a2 * sv.w;
    }
    if (q) red[q - 1][tt] = acc;
    __syncthreads();
    if (q == 0) {
        const float4 r0 = red[0][tt], r1 = red[1][tt], r2 = red[2][tt];
        acc.x += r0.x + r1.x + r2.x;
        acc.y += r0.y + r1.y + r2.y;
        acc.z += r0.z + r1.z + r2.z;
        acc.w += r0.w + r1.w + r2.w;
        *(float4*)(out + (size_t)b * Dh + d) = acc;
    }
}

extern "C" void kernel_launch(void* const* d_in, const int* in_sizes, int n_in,
                              void* d_out, int out_size, void* d_ws, size_t ws_size,
                              hipStream_t stream)
{
    const float* s   = (const float*)d_in[0];
    const float* y   = (const float*)d_in[1];
    const float* frc = (const float*)d_in[2];
    float* out = (float*)d_out;
    float* ws  = (float*)d_ws;

    const size_t need = (size_t)WS_END * sizeof(float);
    if (ws_size >= need) {
        // slab path: no atomics anywhere -> NO memset dispatch needed
        gram_kernel<1><<<dim3(Bh * NCH), dim3(256), 0, stream>>>(s, y, frc, ws);
        recur_kernel<1><<<dim3(Bh), dim3(256), 0, stream>>>(ws);
    } else {
        // atomic fallback
        hipMemsetAsync(d_ws, 0, (size_t)WS_ZERO_FLOATS * sizeof(float), stream);
        gram_kernel<0><<<dim3(Bh * NCH), dim3(256), 0, stream>>>(s, y, frc, ws);
        recur_kernel<0><<<dim3(Bh), dim3(256), 0, stream>>>(ws);
    }
    combine_kernel<<<dim3(Bh * CCH), dim3(1024), 0, stream>>>(s, y, frc, ws, out);
}